// Round 1
// baseline (2846.219 us; speedup 1.0000x reference)
//
#include <hip/hip_runtime.h>

#define T_STEPS 23
#define ORD 256
#define HID 512
#define IN_DIM 256
#define NBATCH 8192
#define SLOPE 0.2f
#define LDH (T_STEPS * HID)   // row stride (floats) of out viewed as [b][t][h]

__device__ __forceinline__ float lrelu(float x) { return x >= 0.f ? x : SLOPE * x; }

// ---------------------------------------------------------------------------
// Kernel 1: V[k][i] = (A^k @ Bv)[i], k = 0..22. One block, 256 threads.
__global__ void vchain_kernel(const float* __restrict__ A,
                              const float* __restrict__ Bv,
                              float* __restrict__ V) {
    __shared__ float v[ORD];
    int i = threadIdx.x;
    v[i] = Bv[i];
    __syncthreads();
    for (int k = 0; k < T_STEPS; ++k) {
        V[k * ORD + i] = v[i];
        float a = 0.f;
        const float4* ar = (const float4*)(A + i * ORD);
        const float4* vr = (const float4*)v;
        #pragma unroll 8
        for (int t = 0; t < ORD / 4; ++t) {
            float4 a4 = ar[t];
            float4 v4 = vr[t];
            a += a4.x * v4.x + a4.y * v4.y + a4.z * v4.z + a4.w * v4.w;
        }
        __syncthreads();
        v[i] = a;
        __syncthreads();
    }
}

// ---------------------------------------------------------------------------
// Kernel 2: wtab[k][j] = sum_i W_m[j][i] * V[k][i].  grid (23, 8), 64 threads.
__global__ void wtab_kernel(const float* __restrict__ Wm,
                            const float* __restrict__ V,
                            float* __restrict__ wtab) {
    __shared__ float vs[ORD];
    int k = blockIdx.x;
    int j = blockIdx.y * 64 + threadIdx.x;
    ((float4*)vs)[threadIdx.x] = ((const float4*)(V + k * ORD))[threadIdx.x];
    __syncthreads();
    float a = 0.f;
    const float4* wr = (const float4*)(Wm + j * ORD);
    const float4* vr = (const float4*)vs;
    #pragma unroll 8
    for (int i = 0; i < ORD / 4; ++i) {
        float4 w4 = wr[i];
        float4 v4 = vr[i];
        a += w4.x * v4.x + w4.y * v4.y + w4.z * v4.z + w4.w * v4.w;
    }
    wtab[k * HID + j] = a;
}

// ---------------------------------------------------------------------------
// Kernel 3: u[r] = dot(X[r, :], e_x), r = b*23 + t over 188416 rows.
// One wave per row, 4 waves per block.
__global__ void u_kernel(const float* __restrict__ X,
                         const float* __restrict__ ex,
                         float* __restrict__ u) {
    int row = blockIdx.x * 4 + (threadIdx.x >> 6);
    int lane = threadIdx.x & 63;
    const float4* xp = (const float4*)(X + (size_t)row * IN_DIM);
    const float4* ep = (const float4*)ex;
    float4 x4 = xp[lane];
    float4 e4 = ep[lane];
    float acc = x4.x * e4.x + x4.y * e4.y + x4.z * e4.z + x4.w * e4.w;
    #pragma unroll
    for (int off = 32; off; off >>= 1) acc += __shfl_down(acc, off);
    if (lane == 0) u[row] = acc;
}

// ---------------------------------------------------------------------------
// Kernel 4: C[r][n] = sum_k X[r][k] * Wx[k][n].  M=188416, K=256, N=512.
// 64x64 tile, BK=16, 256 threads, 4x4 per thread. Writes into d_out.
__global__ __launch_bounds__(256) void gemm_xwx(const float* __restrict__ X,
                                                const float* __restrict__ Wx,
                                                float* __restrict__ out) {
    __shared__ float As[16][68];
    __shared__ float Bs[16][68];
    int tid = threadIdx.x;
    int row0 = blockIdx.x * 64;
    int col0 = blockIdx.y * 64;
    int tx = tid & 15, ty = tid >> 4;
    int am = tid >> 2, ak4 = tid & 3;   // A-load: row am, k-quad ak4
    float acc[4][4] = {};
    for (int k0 = 0; k0 < 256; k0 += 16) {
        float4 av = *(const float4*)(X + (size_t)(row0 + am) * IN_DIM + k0 + ak4 * 4);
        float4 bv = *(const float4*)(Wx + (size_t)(k0 + ty) * HID + col0 + tx * 4);
        __syncthreads();
        As[ak4 * 4 + 0][am] = av.x;
        As[ak4 * 4 + 1][am] = av.y;
        As[ak4 * 4 + 2][am] = av.z;
        As[ak4 * 4 + 3][am] = av.w;
        *(float4*)&Bs[ty][tx * 4] = bv;
        __syncthreads();
        #pragma unroll
        for (int kk = 0; kk < 16; ++kk) {
            float4 a4 = *(const float4*)&As[kk][ty * 4];
            float4 b4 = *(const float4*)&Bs[kk][tx * 4];
            float a[4] = {a4.x, a4.y, a4.z, a4.w};
            float b[4] = {b4.x, b4.y, b4.z, b4.w};
            #pragma unroll
            for (int i = 0; i < 4; ++i)
                #pragma unroll
                for (int j = 0; j < 4; ++j)
                    acc[i][j] += a[i] * b[j];
        }
    }
    #pragma unroll
    for (int i = 0; i < 4; ++i) {
        float4 v = make_float4(acc[i][0], acc[i][1], acc[i][2], acc[i][3]);
        *(float4*)(out + (size_t)(row0 + ty * 4 + i) * HID + col0 + tx * 4) = v;
    }
}

// ---------------------------------------------------------------------------
// Kernel 5: out[b][t][j] += sum_{s<=t} u[b][s] * wtab[t-s][j].
// One block per b, 512 threads (one per j). wtab taps in registers.
__global__ __launch_bounds__(512) void memconv_kernel(const float* __restrict__ u,
                                                      const float* __restrict__ wtab,
                                                      float* __restrict__ out) {
    int b = blockIdx.x, j = threadIdx.x;
    __shared__ float us[T_STEPS];
    if (j < T_STEPS) us[j] = u[b * T_STEPS + j];
    float w[T_STEPS];
    #pragma unroll
    for (int k = 0; k < T_STEPS; ++k) w[k] = wtab[k * HID + j];
    __syncthreads();
    float* ob = out + (size_t)b * LDH + j;
    #pragma unroll
    for (int t = 0; t < T_STEPS; ++t) {
        float acc = 0.f;
        #pragma unroll
        for (int s = 0; s <= t; ++s) acc += us[s] * w[t - s];
        ob[t * HID] += acc;
    }
}

// ---------------------------------------------------------------------------
// Kernel 6: h_0 = leakyrelu(pre_0)  (no h_{-1} term). Elementwise over t=0 slices.
__global__ void leaky0_kernel(float* __restrict__ out) {
    int idx = blockIdx.x * blockDim.x + threadIdx.x;  // over 8192*128 float4s
    int b = idx >> 7, j4 = idx & 127;
    float4* p = (float4*)(out + (size_t)b * LDH) + j4;
    float4 v = *p;
    v.x = lrelu(v.x); v.y = lrelu(v.y); v.z = lrelu(v.z); v.w = lrelu(v.w);
    *p = v;
}

// ---------------------------------------------------------------------------
// Kernel 7: recurrent step t:
//   out[b][t][n] = lrelu(out[b][t][n] + sum_k out[b][t-1][k] * Wh[n][k])
// Hprev = out + (t-1)*512, Hcur = out + t*512, row stride LDH.
// 64x64 tile, BK=16, NT layout (Wh is [n][k], transposed into LDS).
__global__ __launch_bounds__(256) void gemm_rec(const float* __restrict__ Hprev,
                                                const float* __restrict__ Wh,
                                                float* __restrict__ Hcur) {
    __shared__ float As[16][68];
    __shared__ float Bs[16][68];
    int tid = threadIdx.x;
    int row0 = blockIdx.x * 64;
    int col0 = blockIdx.y * 64;
    int tx = tid & 15, ty = tid >> 4;
    int am = tid >> 2, ak4 = tid & 3;   // A-load and B-load mapping (both transpose)
    float acc[4][4] = {};
    for (int k0 = 0; k0 < HID; k0 += 16) {
        float4 av = *(const float4*)(Hprev + (size_t)(row0 + am) * LDH + k0 + ak4 * 4);
        float4 bv = *(const float4*)(Wh + (size_t)(col0 + am) * HID + k0 + ak4 * 4);
        __syncthreads();
        As[ak4 * 4 + 0][am] = av.x;
        As[ak4 * 4 + 1][am] = av.y;
        As[ak4 * 4 + 2][am] = av.z;
        As[ak4 * 4 + 3][am] = av.w;
        Bs[ak4 * 4 + 0][am] = bv.x;
        Bs[ak4 * 4 + 1][am] = bv.y;
        Bs[ak4 * 4 + 2][am] = bv.z;
        Bs[ak4 * 4 + 3][am] = bv.w;
        __syncthreads();
        #pragma unroll
        for (int kk = 0; kk < 16; ++kk) {
            float4 a4 = *(const float4*)&As[kk][ty * 4];
            float4 b4 = *(const float4*)&Bs[kk][tx * 4];
            float a[4] = {a4.x, a4.y, a4.z, a4.w};
            float b[4] = {b4.x, b4.y, b4.z, b4.w};
            #pragma unroll
            for (int i = 0; i < 4; ++i)
                #pragma unroll
                for (int j = 0; j < 4; ++j)
                    acc[i][j] += a[i] * b[j];
        }
    }
    #pragma unroll
    for (int i = 0; i < 4; ++i) {
        float* cp = Hcur + (size_t)(row0 + ty * 4 + i) * LDH + col0 + tx * 4;
        float4 c = *(const float4*)cp;
        float4 r;
        r.x = lrelu(c.x + acc[i][0]);
        r.y = lrelu(c.y + acc[i][1]);
        r.z = lrelu(c.z + acc[i][2]);
        r.w = lrelu(c.w + acc[i][3]);
        *(float4*)cp = r;
    }
}

// ---------------------------------------------------------------------------
extern "C" void kernel_launch(void* const* d_in, const int* in_sizes, int n_in,
                              void* d_out, int out_size, void* d_ws, size_t ws_size,
                              hipStream_t stream) {
    const float* X  = (const float*)d_in[0];  // (8192, 23, 256)
    const float* A  = (const float*)d_in[1];  // (256, 256)
    const float* Bv = (const float*)d_in[2];  // (256, 1)
    const float* Wh = (const float*)d_in[3];  // (512, 512)
    const float* Wm = (const float*)d_in[4];  // (512, 256)
    const float* Wx = (const float*)d_in[5];  // (256, 512)
    const float* ex = (const float*)d_in[6];  // (256, 1)
    float* out = (float*)d_out;               // (8192, 23, 512)

    // workspace layout (floats): u [188416] | V [23*256] | wtab [23*512]
    float* u    = (float*)d_ws;
    float* V    = u + NBATCH * T_STEPS;
    float* wtab = V + T_STEPS * ORD;

    const int nrows = NBATCH * T_STEPS;  // 188416

    // 1) memory-kernel taps: V[k] = A^k Bv ; wtab[k] = W_m V[k]
    vchain_kernel<<<1, 256, 0, stream>>>(A, Bv, V);
    wtab_kernel<<<dim3(T_STEPS, HID / 64), 64, 0, stream>>>(Wm, V, wtab);

    // 2) u = X @ e_x
    u_kernel<<<nrows / 4, 256, 0, stream>>>(X, ex, u);

    // 3) out = X @ W_x (all rows)
    gemm_xwx<<<dim3(nrows / 64, HID / 64), 256, 0, stream>>>(X, Wx, out);

    // 4) out += causal conv of u with wtab
    memconv_kernel<<<NBATCH, HID, 0, stream>>>(u, wtab, out);

    // 5) t = 0: h_0 = lrelu(pre_0)
    leaky0_kernel<<<(NBATCH * (HID / 4)) / 256, 256, 0, stream>>>(out);

    // 6) t = 1..22: h_t = lrelu(pre_t + h_{t-1} @ Wh^T), in place in d_out
    for (int t = 1; t < T_STEPS; ++t) {
        gemm_rec<<<dim3(NBATCH / 64, HID / 64), 256, 0, stream>>>(
            out + (size_t)(t - 1) * HID, Wh, out + (size_t)t * HID);
    }
}